// Round 1
// baseline (326.587 us; speedup 1.0000x reference)
//
#include <hip/hip_runtime.h>
#include <hip/hip_bf16.h>
#include <cstdint>
#include <cstddef>

// Problem constants
constexpr int T_Q   = 32400;   // BEV queries
constexpr int T_PAD = 32512;   // padded to 254*128
constexpr int S_K   = 16896;   // feature keys (= 132*128, no pad needed)
constexpr int E_DIM = 256;
constexpr int HID   = 512;

typedef __bf16 bf16x8 __attribute__((ext_vector_type(8)));
typedef float  f32x4  __attribute__((ext_vector_type(4)));

__device__ __forceinline__ void async16(const __hip_bfloat16* gp, __hip_bfloat16* lp) {
    __builtin_amdgcn_global_load_lds(
        (const __attribute__((address_space(1))) void*)(gp),
        (__attribute__((address_space(3))) void*)(lp), 16, 0, 0);
}

__device__ __forceinline__ float b2f(unsigned short u) {
    return __uint_as_float(((unsigned)u) << 16);
}

// ---------------------------------------------------------------------------
// fp32 -> bf16 cast with zero-padding past `valid` elements (row-pad for GEMM M)
__global__ __launch_bounds__(256) void cast_pad(const float* __restrict__ src,
                                                __hip_bfloat16* __restrict__ dst,
                                                int valid, int total) {
    int i = (blockIdx.x * 256 + threadIdx.x) * 4;
    if (i >= total) return;
    float4 f = make_float4(0.f, 0.f, 0.f, 0.f);
    if (i < valid) f = *(const float4*)(src + i);
    union { ushort4 u4; __hip_bfloat16 b[4]; } cv;
    cv.b[0] = __float2bfloat16(f.x);
    cv.b[1] = __float2bfloat16(f.y);
    cv.b[2] = __float2bfloat16(f.z);
    cv.b[3] = __float2bfloat16(f.w);
    *(ushort4*)(dst + i) = cv.u4;
}

// ---------------------------------------------------------------------------
// Transpose the 4 weight matrices (each 2^17 elements) to [N][K] bf16.
// seg 0: q_w1 (K=256,N=512)  seg 1: q_w2 (K=512,N=256)  seg 2: k_w1  seg 3: k_w2
__global__ __launch_bounds__(256) void transpose_w(
    const float* __restrict__ s0, const float* __restrict__ s1,
    const float* __restrict__ s2, const float* __restrict__ s3,
    __hip_bfloat16* __restrict__ d0, __hip_bfloat16* __restrict__ d1,
    __hip_bfloat16* __restrict__ d2, __hip_bfloat16* __restrict__ d3) {
    int idx = blockIdx.x * 256 + threadIdx.x;
    int seg = idx >> 17;
    int r   = idx & ((1 << 17) - 1);
    const float* s = seg == 0 ? s0 : seg == 1 ? s1 : seg == 2 ? s2 : s3;
    __hip_bfloat16* d = seg == 0 ? d0 : seg == 1 ? d1 : seg == 2 ? d2 : d3;
    int kb = (seg & 1) ? 9 : 8;          // log2(K)
    int n = r >> kb;
    int k = r & ((1 << kb) - 1);
    d[r] = __float2bfloat16(s[(k << (17 - kb)) + n]);
}

// ---------------------------------------------------------------------------
// bf16 GEMM: C[M x N] = A[M x K] @ B[K x N], B given transposed as BT[N x K].
// M is implied by grid (multiple of 128). Epilogue: (+bias), optional relu, *scale,
// store bf16. m97-style: BM=BN=128, BK=32, 4 waves x (4x4) mfma_16x16x32 tiles,
// global_load_lds(16B) staging, 16B-unit XOR swizzle (2-way bank alias = free).
constexpr int BM = 128, BN = 128, BK = 32;

__global__ __launch_bounds__(256) void gemm_bf16(
    const __hip_bfloat16* __restrict__ A,
    const __hip_bfloat16* __restrict__ BT,
    const float* __restrict__ bias,
    __hip_bfloat16* __restrict__ C,
    int K, int N, int relu, float scale) {
    __shared__ __hip_bfloat16 As[BM * BK];
    __shared__ __hip_bfloat16 Bs[BN * BK];

    const int ntiles = N >> 7;
    const int tm = blockIdx.x / ntiles;
    const int tn = blockIdx.x - tm * ntiles;
    const size_t m0 = (size_t)tm * BM;
    const int n0 = tn * BN;

    const int tid = threadIdx.x;
    const int w = tid >> 6, l = tid & 63;
    const int lm = l & 15, lq = l >> 4;
    const int wm = (w >> 1) << 6, wn = (w & 1) << 6;

    // staging geometry: each wave stages 1KB chunks; lane l -> row (l>>2), 16B unit (l&3)
    const int srow = l >> 2;                    // 0..15 within a 16-row chunk
    const int scol = (((l & 3) ^ (srow & 3)) << 3); // swizzled element col in [0,32)

    f32x4 acc[4][4] = {};

    for (int k0 = 0; k0 < K; k0 += BK) {
#pragma unroll
        for (int c = 0; c < 2; ++c) {
            int r = c * 64 + w * 16 + srow;
            async16(A  + (m0 + r) * K + k0 + scol, As + (c * 64 + w * 16) * BK);
            async16(BT + (size_t)(n0 + r) * K + k0 + scol, Bs + (c * 64 + w * 16) * BK);
        }
        __syncthreads();

        const int rsw = ((lq ^ (lm & 3)) << 3);  // swizzled read offset (elements)
        bf16x8 af[4], bfr[4];
#pragma unroll
        for (int mi = 0; mi < 4; ++mi) {
            int row = wm + mi * 16 + lm;
            af[mi] = *(const bf16x8*)(As + row * BK + rsw);
        }
#pragma unroll
        for (int ni = 0; ni < 4; ++ni) {
            int row = wn + ni * 16 + lm;
            bfr[ni] = *(const bf16x8*)(Bs + row * BK + rsw);
        }
#pragma unroll
        for (int mi = 0; mi < 4; ++mi)
#pragma unroll
            for (int ni = 0; ni < 4; ++ni)
                acc[mi][ni] = __builtin_amdgcn_mfma_f32_16x16x32_bf16(
                    af[mi], bfr[ni], acc[mi][ni], 0, 0, 0);
        __syncthreads();
    }

    // epilogue: C/D layout col = lane&15, row = (lane>>4)*4 + reg  [m89-verified]
#pragma unroll
    for (int ni = 0; ni < 4; ++ni) {
        int col = n0 + wn + ni * 16 + lm;
        float bv = bias[col];
#pragma unroll
        for (int mi = 0; mi < 4; ++mi) {
            size_t rowb = m0 + wm + mi * 16 + lq * 4;
#pragma unroll
            for (int r = 0; r < 4; ++r) {
                float vv = acc[mi][ni][r] + bv;
                if (relu) vv = fmaxf(vv, 0.f);
                C[(rowb + r) * N + col] = __float2bfloat16(vv * scale);
            }
        }
    }
}

// ---------------------------------------------------------------------------
// Attention: one wave per BEV query. Head = lane>>3 (8 lanes x 4 elems = D=32).
// Online softmax over the L (<=32) points of the query's interval.
__global__ __launch_bounds__(256) void attn_kernel(
    const __hip_bfloat16* __restrict__ q,   // [T_PAD x 256] (pre-scaled)
    const __hip_bfloat16* __restrict__ k,   // [S_K x 256]
    const __hip_bfloat16* __restrict__ v,   // [S_K x 256]
    const int* __restrict__ ranks_feat,
    const int* __restrict__ starts,
    const int* __restrict__ lens,
    float* __restrict__ out) {              // [T_Q x 256]
    int t = blockIdx.x * 4 + (threadIdx.x >> 6);
    if (t >= T_Q) return;
    int l = threadIdx.x & 63;
    int start = starts[t];
    int L = lens[t];

    // preload the interval's feature indices into lanes 0..L-1
    int myf = (l < L) ? ranks_feat[start + l] : 0;

    ushort4 qu = *(const ushort4*)(q + (size_t)t * 256 + l * 4);
    float q0 = b2f(qu.x), q1 = b2f(qu.y), q2 = b2f(qu.z), q3 = b2f(qu.w);

    float m = -INFINITY, s = 0.f;
    float a0 = 0.f, a1 = 0.f, a2 = 0.f, a3 = 0.f;

    for (int j = 0; j < L; ++j) {
        int f = __shfl(myf, j);
        const __hip_bfloat16* kp = k + (size_t)f * 256 + l * 4;
        ushort4 ku = *(const ushort4*)kp;
        float wv = q0 * b2f(ku.x) + q1 * b2f(ku.y) + q2 * b2f(ku.z) + q3 * b2f(ku.w);
        // reduce across the 8 lanes of this head (lanes differing in bits 0..2)
        wv += __shfl_xor(wv, 1);
        wv += __shfl_xor(wv, 2);
        wv += __shfl_xor(wv, 4);

        float mn = fmaxf(m, wv);
        float al = __expf(m - mn);    // first iter: exp(-inf) = 0
        float p  = __expf(wv - mn);
        s = s * al + p;

        const __hip_bfloat16* vp = v + (size_t)f * 256 + l * 4;
        ushort4 vu = *(const ushort4*)vp;
        a0 = a0 * al + p * b2f(vu.x);
        a1 = a1 * al + p * b2f(vu.y);
        a2 = a2 * al + p * b2f(vu.z);
        a3 = a3 * al + p * b2f(vu.w);
        m = mn;
    }
    float inv = 1.f / s;
    float4 o = make_float4(a0 * inv, a1 * inv, a2 * inv, a3 * inv);
    *(float4*)(out + (size_t)t * 256 + l * 4) = o;
}

// ---------------------------------------------------------------------------
extern "C" void kernel_launch(void* const* d_in, const int* in_sizes, int n_in,
                              void* d_out, int out_size, void* d_ws, size_t ws_size,
                              hipStream_t stream) {
    const float* q_in   = (const float*)d_in[0];
    const float* key_in = (const float*)d_in[1];
    const float* val_in = (const float*)d_in[2];
    const float* q_w1   = (const float*)d_in[3];
    const float* q_b1   = (const float*)d_in[4];
    const float* q_w2   = (const float*)d_in[5];
    const float* q_b2   = (const float*)d_in[6];
    const float* k_w1   = (const float*)d_in[7];
    const float* k_b1   = (const float*)d_in[8];
    const float* k_w2   = (const float*)d_in[9];
    const float* k_b2   = (const float*)d_in[10];
    const int* ranks_feat = (const int*)d_in[11];
    const int* starts     = (const int*)d_in[13];
    const int* lens       = (const int*)d_in[14];
    float* out = (float*)d_out;

    char* ws = (char*)d_ws;
    size_t off = 0;
    auto alloc = [&](size_t bytes) {
        char* p = ws + off;
        off += (bytes + 255) & ~(size_t)255;
        return p;
    };
    __hip_bfloat16* qA   = (__hip_bfloat16*)alloc((size_t)T_PAD * E_DIM * 2);
    __hip_bfloat16* hidQ = (__hip_bfloat16*)alloc((size_t)T_PAD * HID * 2);
    __hip_bfloat16* qMl  = (__hip_bfloat16*)alloc((size_t)T_PAD * E_DIM * 2);
    __hip_bfloat16* kA   = (__hip_bfloat16*)alloc((size_t)S_K * E_DIM * 2);
    __hip_bfloat16* hidK = (__hip_bfloat16*)alloc((size_t)S_K * HID * 2);
    __hip_bfloat16* kMl  = (__hip_bfloat16*)alloc((size_t)S_K * E_DIM * 2);
    __hip_bfloat16* vB   = (__hip_bfloat16*)alloc((size_t)S_K * E_DIM * 2);
    __hip_bfloat16* w1qT = (__hip_bfloat16*)alloc((size_t)HID * E_DIM * 2);
    __hip_bfloat16* w2qT = (__hip_bfloat16*)alloc((size_t)E_DIM * HID * 2);
    __hip_bfloat16* w1kT = (__hip_bfloat16*)alloc((size_t)HID * E_DIM * 2);
    __hip_bfloat16* w2kT = (__hip_bfloat16*)alloc((size_t)E_DIM * HID * 2);
    (void)ws_size; (void)n_in; (void)in_sizes; (void)out_size;

    // casts (with M-padding for q)
    cast_pad<<<(T_PAD * E_DIM / 4) / 256, 256, 0, stream>>>(q_in, qA, T_Q * E_DIM, T_PAD * E_DIM);
    cast_pad<<<(S_K * E_DIM / 4) / 256, 256, 0, stream>>>(key_in, kA, S_K * E_DIM, S_K * E_DIM);
    cast_pad<<<(S_K * E_DIM / 4) / 256, 256, 0, stream>>>(val_in, vB, S_K * E_DIM, S_K * E_DIM);
    transpose_w<<<2048, 256, 0, stream>>>(q_w1, q_w2, k_w1, k_w2, w1qT, w2qT, w1kT, w2kT);

    const float qscale = 0.17677669529663687f;  // 1/sqrt(32)
    // q MLP
    gemm_bf16<<<(T_PAD / 128) * (HID / 128), 256, 0, stream>>>(qA, w1qT, q_b1, hidQ, E_DIM, HID, 1, 1.0f);
    gemm_bf16<<<(T_PAD / 128) * (E_DIM / 128), 256, 0, stream>>>(hidQ, w2qT, q_b2, qMl, HID, E_DIM, 0, qscale);
    // k MLP
    gemm_bf16<<<(S_K / 128) * (HID / 128), 256, 0, stream>>>(kA, w1kT, k_b1, hidK, E_DIM, HID, 1, 1.0f);
    gemm_bf16<<<(S_K / 128) * (E_DIM / 128), 256, 0, stream>>>(hidK, w2kT, k_b2, kMl, HID, E_DIM, 0, 1.0f);
    // attention
    attn_kernel<<<T_Q / 4, 256, 0, stream>>>(qMl, kMl, vB, ranks_feat, starts, lens, out);
}

// Round 2
// 318.622 us; speedup vs baseline: 1.0250x; 1.0250x over previous
//
#include <hip/hip_runtime.h>
#include <hip/hip_bf16.h>
#include <cstdint>
#include <cstddef>

// Problem constants
constexpr int T_Q   = 32400;   // BEV queries
constexpr int T_PAD = 32512;   // padded to 254*128
constexpr int S_K   = 16896;   // feature keys (= 132*128)
constexpr int E_DIM = 256;
constexpr int HID   = 512;

typedef __bf16 bf16x8 __attribute__((ext_vector_type(8)));
typedef float  f32x4  __attribute__((ext_vector_type(4)));

__device__ __forceinline__ void async16(const __hip_bfloat16* gp, __hip_bfloat16* lp) {
    __builtin_amdgcn_global_load_lds(
        (const __attribute__((address_space(1))) void*)(gp),
        (__attribute__((address_space(3))) void*)(lp), 16, 0, 0);
}

__device__ __forceinline__ float b2f(unsigned short u) {
    return __uint_as_float(((unsigned)u) << 16);
}

// ---------------------------------------------------------------------------
// prep: fused fp32->bf16 casts (q with M-pad, key, value) + coalesced weight
// transpose to [N][K] bf16 via LDS tiles.
// Block ranges: [0,8128) q-cast, [8128,12352) k-cast, [12352,16576) v-cast,
//               [16576,16704) transpose (4 matrices x 32 tiles of 64x64).
constexpr int NB_Q = (T_PAD * E_DIM / 4) / 256;   // 8128
constexpr int NB_K = (S_K * E_DIM / 4) / 256;     // 4224
constexpr int NB_PREP = NB_Q + NB_K + NB_K + 128;

__global__ __launch_bounds__(256) void prep(
    const float* __restrict__ q_in, const float* __restrict__ key_in,
    const float* __restrict__ val_in,
    const float* __restrict__ s0, const float* __restrict__ s1,
    const float* __restrict__ s2, const float* __restrict__ s3,
    __hip_bfloat16* __restrict__ qA, __hip_bfloat16* __restrict__ kA,
    __hip_bfloat16* __restrict__ vB,
    __hip_bfloat16* __restrict__ d0, __hip_bfloat16* __restrict__ d1,
    __hip_bfloat16* __restrict__ d2, __hip_bfloat16* __restrict__ d3) {
    __shared__ float tb[64][65];
    const int b = blockIdx.x;
    const int tid = threadIdx.x;

    if (b < NB_Q + 2 * NB_K) {
        const float* src;
        __hip_bfloat16* dst;
        int bl, valid;
        if (b < NB_Q) { src = q_in; dst = qA; bl = b; valid = T_Q * E_DIM; }
        else if (b < NB_Q + NB_K) { src = key_in; dst = kA; bl = b - NB_Q; valid = S_K * E_DIM; }
        else { src = val_in; dst = vB; bl = b - NB_Q - NB_K; valid = S_K * E_DIM; }
        int i = (bl * 256 + tid) * 4;
        float4 f = make_float4(0.f, 0.f, 0.f, 0.f);
        if (i < valid) f = *(const float4*)(src + i);
        union { ushort4 u4; __hip_bfloat16 bb[4]; } cv;
        cv.bb[0] = __float2bfloat16(f.x);
        cv.bb[1] = __float2bfloat16(f.y);
        cv.bb[2] = __float2bfloat16(f.z);
        cv.bb[3] = __float2bfloat16(f.w);
        *(ushort4*)(dst + i) = cv.u4;
        return;
    }

    // transpose: matrix m (0:q_w1 K256 N512, 1:q_w2 K512 N256, 2:k_w1, 3:k_w2)
    int tloc = b - (NB_Q + 2 * NB_K);
    int m = tloc >> 5;
    int tt = tloc & 31;
    const float* S = m == 0 ? s0 : m == 1 ? s1 : m == 2 ? s2 : s3;
    __hip_bfloat16* D = m == 0 ? d0 : m == 1 ? d1 : m == 2 ? d2 : d3;
    int Kd, Nd, kt, nt;
    if ((m & 1) == 0) { Kd = 256; Nd = 512; kt = tt & 3; nt = tt >> 2; }
    else              { Kd = 512; Nd = 256; kt = tt & 7; nt = tt >> 3; }
    int tx = tid & 63, ty = tid >> 6;
#pragma unroll
    for (int p = 0; p < 16; ++p) {
        int row = ty * 16 + p;
        tb[row][tx] = S[(size_t)(kt * 64 + row) * Nd + nt * 64 + tx];
    }
    __syncthreads();
#pragma unroll
    for (int p = 0; p < 16; ++p) {
        int row = ty * 16 + p;
        D[(size_t)(nt * 64 + row) * Kd + kt * 64 + tx] = __float2bfloat16(tb[tx][row]);
    }
}

// ---------------------------------------------------------------------------
// bf16 GEMM (m97-style): C[MxN] = A[MxK] @ BT[NxK]^T, epilogue bias/relu/scale.
constexpr int BM = 128, BN = 128, BK = 32;

__global__ __launch_bounds__(256) void gemm_bf16(
    const __hip_bfloat16* __restrict__ A,
    const __hip_bfloat16* __restrict__ BT,
    const float* __restrict__ bias,
    __hip_bfloat16* __restrict__ C,
    int K, int N, int relu, float scale) {
    __shared__ __hip_bfloat16 As[BM * BK];
    __shared__ __hip_bfloat16 Bs[BN * BK];

    const int ntiles = N >> 7;
    const int tm = blockIdx.x / ntiles;
    const int tn = blockIdx.x - tm * ntiles;
    const size_t m0 = (size_t)tm * BM;
    const int n0 = tn * BN;

    const int tid = threadIdx.x;
    const int w = tid >> 6, l = tid & 63;
    const int lm = l & 15, lq = l >> 4;
    const int wm = (w >> 1) << 6, wn = (w & 1) << 6;

    const int srow = l >> 2;
    const int scol = (((l & 3) ^ (srow & 3)) << 3);

    f32x4 acc[4][4] = {};

    for (int k0 = 0; k0 < K; k0 += BK) {
#pragma unroll
        for (int c = 0; c < 2; ++c) {
            int r = c * 64 + w * 16 + srow;
            async16(A  + (m0 + r) * K + k0 + scol, As + (c * 64 + w * 16) * BK);
            async16(BT + (size_t)(n0 + r) * K + k0 + scol, Bs + (c * 64 + w * 16) * BK);
        }
        __syncthreads();

        const int rsw = ((lq ^ (lm & 3)) << 3);
        bf16x8 af[4], bfr[4];
#pragma unroll
        for (int mi = 0; mi < 4; ++mi)
            af[mi] = *(const bf16x8*)(As + (wm + mi * 16 + lm) * BK + rsw);
#pragma unroll
        for (int ni = 0; ni < 4; ++ni)
            bfr[ni] = *(const bf16x8*)(Bs + (wn + ni * 16 + lm) * BK + rsw);
#pragma unroll
        for (int mi = 0; mi < 4; ++mi)
#pragma unroll
            for (int ni = 0; ni < 4; ++ni)
                acc[mi][ni] = __builtin_amdgcn_mfma_f32_16x16x32_bf16(
                    af[mi], bfr[ni], acc[mi][ni], 0, 0, 0);
        __syncthreads();
    }

#pragma unroll
    for (int ni = 0; ni < 4; ++ni) {
        int col = n0 + wn + ni * 16 + lm;
        float bv = bias[col];
#pragma unroll
        for (int mi = 0; mi < 4; ++mi) {
            size_t rowb = m0 + wm + mi * 16 + lq * 4;
#pragma unroll
            for (int r = 0; r < 4; ++r) {
                float vv = acc[mi][ni][r] + bv;
                if (relu) vv = fmaxf(vv, 0.f);
                C[(rowb + r) * N + col] = __float2bfloat16(vv * scale);
            }
        }
    }
}

// ---------------------------------------------------------------------------
// Attention: one wave per BEV query, head = lane>>3 (8 lanes x 4 elems = D=32).
// Chunked (4 keys) online softmax with a double-buffered register prefetch
// pipeline (8 gather loads in flight per wave). Feature indices via
// wave-uniform scalar loads.
#define PREF(K0,K1,K2,K3,V0,V1,V2,V3,J0)                                    \
    {                                                                        \
        int j_ = (J0);                                                       \
        int i0 = su + j_ + 0; i0 = i0 < nmax ? i0 : nmax;                    \
        int i1 = su + j_ + 1; i1 = i1 < nmax ? i1 : nmax;                    \
        int i2 = su + j_ + 2; i2 = i2 < nmax ? i2 : nmax;                    \
        int i3 = su + j_ + 3; i3 = i3 < nmax ? i3 : nmax;                    \
        int f0 = rf[i0], f1 = rf[i1], f2 = rf[i2], f3 = rf[i3];              \
        K0 = *(const ushort4*)(kp + (size_t)f0 * 256 + l4);                  \
        V0 = *(const ushort4*)(vp + (size_t)f0 * 256 + l4);                  \
        K1 = *(const ushort4*)(kp + (size_t)f1 * 256 + l4);                  \
        V1 = *(const ushort4*)(vp + (size_t)f1 * 256 + l4);                  \
        K2 = *(const ushort4*)(kp + (size_t)f2 * 256 + l4);                  \
        V2 = *(const ushort4*)(vp + (size_t)f2 * 256 + l4);                  \
        K3 = *(const ushort4*)(kp + (size_t)f3 * 256 + l4);                  \
        V3 = *(const ushort4*)(vp + (size_t)f3 * 256 + l4);                  \
    }

#define DOT4(K_) fmaf(q0, b2f(K_.x), fmaf(q1, b2f(K_.y), fmaf(q2, b2f(K_.z), q3 * b2f(K_.w))))

#define PROC(K0,K1,K2,K3,V0,V1,V2,V3,J0)                                    \
    {                                                                        \
        float w0 = DOT4(K0), w1 = DOT4(K1), w2 = DOT4(K2), w3 = DOT4(K3);   \
        w0 += __shfl_xor(w0, 1); w1 += __shfl_xor(w1, 1);                   \
        w2 += __shfl_xor(w2, 1); w3 += __shfl_xor(w3, 1);                   \
        w0 += __shfl_xor(w0, 2); w1 += __shfl_xor(w1, 2);                   \
        w2 += __shfl_xor(w2, 2); w3 += __shfl_xor(w3, 2);                   \
        w0 += __shfl_xor(w0, 4); w1 += __shfl_xor(w1, 4);                   \
        w2 += __shfl_xor(w2, 4); w3 += __shfl_xor(w3, 4);                   \
        if ((J0) + 1 >= L) w1 = -1e30f;                                      \
        if ((J0) + 2 >= L) w2 = -1e30f;                                      \
        if ((J0) + 3 >= L) w3 = -1e30f;                                      \
        float mw = fmaxf(fmaxf(w0, w1), fmaxf(w2, w3));                      \
        float mn = fmaxf(m, mw);                                             \
        float al = __expf(m - mn); m = mn;                                   \
        float p0 = __expf(w0 - mn), p1 = __expf(w1 - mn);                    \
        float p2 = __expf(w2 - mn), p3 = __expf(w3 - mn);                    \
        s = s * al + ((p0 + p1) + (p2 + p3));                                \
        a0 = fmaf(p3, b2f(V3.x), fmaf(p2, b2f(V2.x), fmaf(p1, b2f(V1.x), fmaf(p0, b2f(V0.x), a0 * al)))); \
        a1 = fmaf(p3, b2f(V3.y), fmaf(p2, b2f(V2.y), fmaf(p1, b2f(V1.y), fmaf(p0, b2f(V0.y), a1 * al)))); \
        a2 = fmaf(p3, b2f(V3.z), fmaf(p2, b2f(V2.z), fmaf(p1, b2f(V1.z), fmaf(p0, b2f(V0.z), a2 * al)))); \
        a3 = fmaf(p3, b2f(V3.w), fmaf(p2, b2f(V2.w), fmaf(p1, b2f(V1.w), fmaf(p0, b2f(V0.w), a3 * al)))); \
    }

__global__ __launch_bounds__(256) void attn_kernel(
    const __hip_bfloat16* __restrict__ q,
    const __hip_bfloat16* __restrict__ kp,
    const __hip_bfloat16* __restrict__ vp,
    const int* __restrict__ rf,
    const int* __restrict__ starts,
    const int* __restrict__ lens,
    int nmax,                               // N_total - 1
    float* __restrict__ out) {
    int t = blockIdx.x * 4 + (threadIdx.x >> 6);
    if (t >= T_Q) return;
    int l = threadIdx.x & 63;
    int l4 = l * 4;
    int su = __builtin_amdgcn_readfirstlane(starts[t]);
    int L  = __builtin_amdgcn_readfirstlane(lens[t]);

    ushort4 qu = *(const ushort4*)(q + (size_t)t * 256 + l4);
    float q0 = b2f(qu.x), q1 = b2f(qu.y), q2 = b2f(qu.z), q3 = b2f(qu.w);

    float m = -INFINITY, s = 0.f;
    float a0 = 0.f, a1 = 0.f, a2 = 0.f, a3 = 0.f;

    ushort4 ak0, ak1, ak2, ak3, av0, av1, av2, av3;
    ushort4 bk0, bk1, bk2, bk3, bv0, bv1, bv2, bv3;

    int Lr = (L + 3) & ~3;
    PREF(ak0, ak1, ak2, ak3, av0, av1, av2, av3, 0);
    for (int j0 = 0; j0 < Lr; j0 += 8) {
        bool hasB = (j0 + 4 < Lr);
        if (hasB) PREF(bk0, bk1, bk2, bk3, bv0, bv1, bv2, bv3, j0 + 4);
        PROC(ak0, ak1, ak2, ak3, av0, av1, av2, av3, j0);
        if (hasB) {
            if (j0 + 8 < Lr) PREF(ak0, ak1, ak2, ak3, av0, av1, av2, av3, j0 + 8);
            PROC(bk0, bk1, bk2, bk3, bv0, bv1, bv2, bv3, j0 + 4);
        }
    }

    float inv = 1.f / s;
    float4 o = make_float4(a0 * inv, a1 * inv, a2 * inv, a3 * inv);
    *(float4*)(out + (size_t)t * 256 + l4) = o;
}

// ---------------------------------------------------------------------------
extern "C" void kernel_launch(void* const* d_in, const int* in_sizes, int n_in,
                              void* d_out, int out_size, void* d_ws, size_t ws_size,
                              hipStream_t stream) {
    const float* q_in   = (const float*)d_in[0];
    const float* key_in = (const float*)d_in[1];
    const float* val_in = (const float*)d_in[2];
    const float* q_w1   = (const float*)d_in[3];
    const float* q_b1   = (const float*)d_in[4];
    const float* q_w2   = (const float*)d_in[5];
    const float* q_b2   = (const float*)d_in[6];
    const float* k_w1   = (const float*)d_in[7];
    const float* k_b1   = (const float*)d_in[8];
    const float* k_w2   = (const float*)d_in[9];
    const float* k_b2   = (const float*)d_in[10];
    const int* ranks_feat = (const int*)d_in[11];
    const int* starts     = (const int*)d_in[13];
    const int* lens       = (const int*)d_in[14];
    float* out = (float*)d_out;
    const int n_points = in_sizes[11];

    char* ws = (char*)d_ws;
    size_t off = 0;
    auto alloc = [&](size_t bytes) {
        char* p = ws + off;
        off += (bytes + 255) & ~(size_t)255;
        return p;
    };
    __hip_bfloat16* qA   = (__hip_bfloat16*)alloc((size_t)T_PAD * E_DIM * 2);
    __hip_bfloat16* hidQ = (__hip_bfloat16*)alloc((size_t)T_PAD * HID * 2);
    __hip_bfloat16* qMl  = (__hip_bfloat16*)alloc((size_t)T_PAD * E_DIM * 2);
    __hip_bfloat16* kA   = (__hip_bfloat16*)alloc((size_t)S_K * E_DIM * 2);
    __hip_bfloat16* hidK = (__hip_bfloat16*)alloc((size_t)S_K * HID * 2);
    __hip_bfloat16* kMl  = (__hip_bfloat16*)alloc((size_t)S_K * E_DIM * 2);
    __hip_bfloat16* vB   = (__hip_bfloat16*)alloc((size_t)S_K * E_DIM * 2);
    __hip_bfloat16* w1qT = (__hip_bfloat16*)alloc((size_t)HID * E_DIM * 2);
    __hip_bfloat16* w2qT = (__hip_bfloat16*)alloc((size_t)E_DIM * HID * 2);
    __hip_bfloat16* w1kT = (__hip_bfloat16*)alloc((size_t)HID * E_DIM * 2);
    __hip_bfloat16* w2kT = (__hip_bfloat16*)alloc((size_t)E_DIM * HID * 2);
    (void)ws_size; (void)n_in; (void)out_size;

    prep<<<NB_PREP, 256, 0, stream>>>(q_in, key_in, val_in,
                                      q_w1, q_w2, k_w1, k_w2,
                                      qA, kA, vB, w1qT, w2qT, w1kT, w2kT);

    const float qscale = 0.17677669529663687f;  // 1/sqrt(32)
    gemm_bf16<<<(T_PAD / 128) * (HID / 128), 256, 0, stream>>>(qA, w1qT, q_b1, hidQ, E_DIM, HID, 1, 1.0f);
    gemm_bf16<<<(T_PAD / 128) * (E_DIM / 128), 256, 0, stream>>>(hidQ, w2qT, q_b2, qMl, HID, E_DIM, 0, qscale);
    gemm_bf16<<<(S_K / 128) * (HID / 128), 256, 0, stream>>>(kA, w1kT, k_b1, hidK, E_DIM, HID, 1, 1.0f);
    gemm_bf16<<<(S_K / 128) * (E_DIM / 128), 256, 0, stream>>>(hidK, w2kT, k_b2, kMl, HID, E_DIM, 0, 1.0f);

    attn_kernel<<<T_Q / 4, 256, 0, stream>>>(qMl, kMl, vB, ranks_feat, starts, lens,
                                             n_points - 1, out);
}

// Round 3
// 313.124 us; speedup vs baseline: 1.0430x; 1.0176x over previous
//
#include <hip/hip_runtime.h>
#include <hip/hip_bf16.h>
#include <cstdint>
#include <cstddef>

// Problem constants
constexpr int T_Q   = 32400;   // BEV queries
constexpr int T_PAD = 32512;   // padded to 254*128
constexpr int S_K   = 16896;   // feature keys (= 132*128)
constexpr int E_DIM = 256;
constexpr int HID   = 512;

typedef __bf16 bf16x8 __attribute__((ext_vector_type(8)));
typedef float  f32x4  __attribute__((ext_vector_type(4)));
typedef unsigned short ushort8v __attribute__((ext_vector_type(8)));

__device__ __forceinline__ void async16(const __hip_bfloat16* gp, __hip_bfloat16* lp) {
    __builtin_amdgcn_global_load_lds(
        (const __attribute__((address_space(1))) void*)(gp),
        (__attribute__((address_space(3))) void*)(lp), 16, 0, 0);
}

__device__ __forceinline__ float b2f(unsigned short u) {
    return __uint_as_float(((unsigned)u) << 16);
}

// ---------------------------------------------------------------------------
// prep: fused fp32->bf16 casts (q with M-pad, key, value->kv cols 256..511)
// + coalesced weight transpose to [N][K] bf16 via LDS tiles.
constexpr int NB_Q = (T_PAD * E_DIM / 4) / 256;   // 8128
constexpr int NB_K = (S_K * E_DIM / 4) / 256;     // 4224
constexpr int NB_PREP = NB_Q + NB_K + NB_K + 128;

__global__ __launch_bounds__(256) void prep(
    const float* __restrict__ q_in, const float* __restrict__ key_in,
    const float* __restrict__ val_in,
    const float* __restrict__ s0, const float* __restrict__ s1,
    const float* __restrict__ s2, const float* __restrict__ s3,
    __hip_bfloat16* __restrict__ qA, __hip_bfloat16* __restrict__ kA,
    __hip_bfloat16* __restrict__ kvB,
    __hip_bfloat16* __restrict__ d0, __hip_bfloat16* __restrict__ d1,
    __hip_bfloat16* __restrict__ d2, __hip_bfloat16* __restrict__ d3) {
    __shared__ float tb[64][65];
    const int b = blockIdx.x;
    const int tid = threadIdx.x;

    if (b < NB_Q + 2 * NB_K) {
        const float* src;
        int bl, valid, isv = 0;
        if (b < NB_Q) { src = q_in; bl = b; valid = T_Q * E_DIM; }
        else if (b < NB_Q + NB_K) { src = key_in; bl = b - NB_Q; valid = S_K * E_DIM; }
        else { src = val_in; bl = b - NB_Q - NB_K; valid = S_K * E_DIM; isv = 1; }
        int i = (bl * 256 + tid) * 4;
        float4 f = make_float4(0.f, 0.f, 0.f, 0.f);
        if (i < valid) f = *(const float4*)(src + i);
        union { ushort4 u4; __hip_bfloat16 bb[4]; } cv;
        cv.bb[0] = __float2bfloat16(f.x);
        cv.bb[1] = __float2bfloat16(f.y);
        cv.bb[2] = __float2bfloat16(f.z);
        cv.bb[3] = __float2bfloat16(f.w);
        if (isv) {
            int r = i >> 8, c = i & 255;   // v goes to kv[r][256+c]
            *(ushort4*)(kvB + (size_t)r * 512 + 256 + c) = cv.u4;
        } else {
            __hip_bfloat16* dst = (b < NB_Q) ? qA : kA;
            *(ushort4*)(dst + i) = cv.u4;
        }
        return;
    }

    // transpose: matrix m (0:q_w1 K256 N512, 1:q_w2 K512 N256, 2:k_w1, 3:k_w2)
    int tloc = b - (NB_Q + 2 * NB_K);
    int m = tloc >> 5;
    int tt = tloc & 31;
    const float* S = m == 0 ? s0 : m == 1 ? s1 : m == 2 ? s2 : s3;
    __hip_bfloat16* D = m == 0 ? d0 : m == 1 ? d1 : m == 2 ? d2 : d3;
    int Kd, Nd, kt, nt;
    if ((m & 1) == 0) { Kd = 256; Nd = 512; kt = tt & 3; nt = tt >> 2; }
    else              { Kd = 512; Nd = 256; kt = tt & 7; nt = tt >> 3; }
    int tx = tid & 63, ty = tid >> 6;
#pragma unroll
    for (int p = 0; p < 16; ++p) {
        int row = ty * 16 + p;
        tb[row][tx] = S[(size_t)(kt * 64 + row) * Nd + nt * 64 + tx];
    }
    __syncthreads();
#pragma unroll
    for (int p = 0; p < 16; ++p) {
        int row = ty * 16 + p;
        D[(size_t)(nt * 64 + row) * Kd + kt * 64 + tx] = __float2bfloat16(tb[tx][row]);
    }
}

// ---------------------------------------------------------------------------
// bf16 GEMM (m97-style): C[MxN] = A[MxK] @ BT[NxK]^T, epilogue bias/relu/scale,
// C row stride ldc (for interleaved kv output).
constexpr int BM = 128, BN = 128, BK = 32;

__global__ __launch_bounds__(256) void gemm_bf16(
    const __hip_bfloat16* __restrict__ A,
    const __hip_bfloat16* __restrict__ BT,
    const float* __restrict__ bias,
    __hip_bfloat16* __restrict__ C,
    int K, int N, int ldc, int relu, float scale) {
    __shared__ __hip_bfloat16 As[BM * BK];
    __shared__ __hip_bfloat16 Bs[BN * BK];

    const int ntiles = N >> 7;
    const int tm = blockIdx.x / ntiles;
    const int tn = blockIdx.x - tm * ntiles;
    const size_t m0 = (size_t)tm * BM;
    const int n0 = tn * BN;

    const int tid = threadIdx.x;
    const int w = tid >> 6, l = tid & 63;
    const int lm = l & 15, lq = l >> 4;
    const int wm = (w >> 1) << 6, wn = (w & 1) << 6;

    const int srow = l >> 2;
    const int scol = (((l & 3) ^ (srow & 3)) << 3);

    f32x4 acc[4][4] = {};

    for (int k0 = 0; k0 < K; k0 += BK) {
#pragma unroll
        for (int c = 0; c < 2; ++c) {
            int r = c * 64 + w * 16 + srow;
            async16(A  + (m0 + r) * K + k0 + scol, As + (c * 64 + w * 16) * BK);
            async16(BT + (size_t)(n0 + r) * K + k0 + scol, Bs + (c * 64 + w * 16) * BK);
        }
        __syncthreads();

        const int rsw = ((lq ^ (lm & 3)) << 3);
        bf16x8 af[4], bfr[4];
#pragma unroll
        for (int mi = 0; mi < 4; ++mi)
            af[mi] = *(const bf16x8*)(As + (wm + mi * 16 + lm) * BK + rsw);
#pragma unroll
        for (int ni = 0; ni < 4; ++ni)
            bfr[ni] = *(const bf16x8*)(Bs + (wn + ni * 16 + lm) * BK + rsw);
#pragma unroll
        for (int mi = 0; mi < 4; ++mi)
#pragma unroll
            for (int ni = 0; ni < 4; ++ni)
                acc[mi][ni] = __builtin_amdgcn_mfma_f32_16x16x32_bf16(
                    af[mi], bfr[ni], acc[mi][ni], 0, 0, 0);
        __syncthreads();
    }

#pragma unroll
    for (int ni = 0; ni < 4; ++ni) {
        int col = n0 + wn + ni * 16 + lm;
        float bv = bias[col];
#pragma unroll
        for (int mi = 0; mi < 4; ++mi) {
            size_t rowb = m0 + wm + mi * 16 + lq * 4;
#pragma unroll
            for (int r = 0; r < 4; ++r) {
                float vv = acc[mi][ni][r] + bv;
                if (relu) vv = fmaxf(vv, 0.f);
                C[(rowb + r) * ldc + col] = __float2bfloat16(vv * scale);
            }
        }
    }
}

// ---------------------------------------------------------------------------
// Attention: one wave per BEV query, TWO points per wave.
// Lane l: half = l>>5 picks the point of the pair, sub = l&31 owns 8 dims
// (head = sub>>2). One dwordx4 load covers one 512B k-row for both points;
// k and v interleaved in kv[S][512]. Indices pre-loaded, ds_bpermute per chunk.
#define APREF(DK, DV, C)                                                    \
    {                                                                       \
        int pidx = ((C) << 1) + half;                                       \
        int f = __builtin_amdgcn_ds_bpermute(pidx << 2, myf);               \
        const __hip_bfloat16* bp = kv + (size_t)f * 512 + sub * 8;          \
        DK = *(const ushort8v*)bp;                                          \
        DV = *(const ushort8v*)(bp + 256);                                  \
    }

#define APROC(KB, VB, C)                                                    \
    {                                                                       \
        float wv = 0.f;                                                     \
        _Pragma("unroll") for (int i = 0; i < 8; ++i)                       \
            wv = fmaf(qf[i], b2f(KB[i]), wv);                               \
        wv += __shfl_xor(wv, 1);                                            \
        wv += __shfl_xor(wv, 2);                                            \
        float wo = __shfl_xor(wv, 32);                                      \
        int pm = ((C) << 1) + half;                                         \
        int po = ((C) << 1) + 1 - half;                                     \
        if (pm >= L) wv = -1e30f;                                           \
        if (po >= L) wo = -1e30f;                                           \
        float mn = fmaxf(m, fmaxf(wv, wo));                                 \
        float al = __expf(m - mn); m = mn;                                  \
        float p = __expf(wv - mn);                                          \
        s = fmaf(s, al, p);                                                 \
        _Pragma("unroll") for (int i = 0; i < 8; ++i)                       \
            a[i] = fmaf(p, b2f(VB[i]), a[i] * al);                          \
    }

__global__ __launch_bounds__(256) void attn_kernel(
    const __hip_bfloat16* __restrict__ q,
    const __hip_bfloat16* __restrict__ kv,
    const int* __restrict__ rf,
    const int* __restrict__ starts,
    const int* __restrict__ lens,
    float* __restrict__ out) {
    int t = blockIdx.x * 4 + (threadIdx.x >> 6);
    if (t >= T_Q) return;
    int l = threadIdx.x & 63;
    int half = l >> 5, sub = l & 31;
    int su = __builtin_amdgcn_readfirstlane(starts[t]);
    int L  = __builtin_amdgcn_readfirstlane(lens[t]);

    // all interval indices into lanes (clamped)
    int li = l < L - 1 ? l : L - 1;
    int myf = rf[su + li];

    ushort8v qu = *(const ushort8v*)(q + (size_t)t * 256 + sub * 8);
    float qf[8];
#pragma unroll
    for (int i = 0; i < 8; ++i) qf[i] = b2f(qu[i]);

    float m = -INFINITY, s = 0.f;
    float a[8] = {0.f, 0.f, 0.f, 0.f, 0.f, 0.f, 0.f, 0.f};

    ushort8v k0v = {}, v0v = {}, k1v = {}, v1v = {}, k2v = {}, v2v = {};

    int nC = (L + 1) >> 1;
    APREF(k0v, v0v, 0);
    if (nC > 1) APREF(k1v, v1v, 1);
    for (int c = 0; c < nC; ++c) {
        if (c + 2 < nC) APREF(k2v, v2v, c + 2);
        APROC(k0v, v0v, c);
        k0v = k1v; v0v = v1v;
        k1v = k2v; v1v = v2v;
    }

    s += __shfl_xor(s, 32);
#pragma unroll
    for (int i = 0; i < 8; ++i) a[i] += __shfl_xor(a[i], 32);
    float inv = 1.f / s;
    float4 o;
    o.x = (half ? a[4] : a[0]) * inv;
    o.y = (half ? a[5] : a[1]) * inv;
    o.z = (half ? a[6] : a[2]) * inv;
    o.w = (half ? a[7] : a[3]) * inv;
    *(float4*)(out + (size_t)t * 256 + sub * 8 + half * 4) = o;
}

// ---------------------------------------------------------------------------
extern "C" void kernel_launch(void* const* d_in, const int* in_sizes, int n_in,
                              void* d_out, int out_size, void* d_ws, size_t ws_size,
                              hipStream_t stream) {
    const float* q_in   = (const float*)d_in[0];
    const float* key_in = (const float*)d_in[1];
    const float* val_in = (const float*)d_in[2];
    const float* q_w1   = (const float*)d_in[3];
    const float* q_b1   = (const float*)d_in[4];
    const float* q_w2   = (const float*)d_in[5];
    const float* q_b2   = (const float*)d_in[6];
    const float* k_w1   = (const float*)d_in[7];
    const float* k_b1   = (const float*)d_in[8];
    const float* k_w2   = (const float*)d_in[9];
    const float* k_b2   = (const float*)d_in[10];
    const int* ranks_feat = (const int*)d_in[11];
    const int* starts     = (const int*)d_in[13];
    const int* lens       = (const int*)d_in[14];
    float* out = (float*)d_out;

    char* ws = (char*)d_ws;
    size_t off = 0;
    auto alloc = [&](size_t bytes) {
        char* p = ws + off;
        off += (bytes + 255) & ~(size_t)255;
        return p;
    };
    __hip_bfloat16* qA   = (__hip_bfloat16*)alloc((size_t)T_PAD * E_DIM * 2);
    __hip_bfloat16* hidQ = (__hip_bfloat16*)alloc((size_t)T_PAD * HID * 2);
    __hip_bfloat16* qMl  = (__hip_bfloat16*)alloc((size_t)T_PAD * E_DIM * 2);
    __hip_bfloat16* kA   = (__hip_bfloat16*)alloc((size_t)S_K * E_DIM * 2);
    __hip_bfloat16* hidK = (__hip_bfloat16*)alloc((size_t)S_K * HID * 2);
    __hip_bfloat16* kvB  = (__hip_bfloat16*)alloc((size_t)S_K * 512 * 2);
    __hip_bfloat16* w1qT = (__hip_bfloat16*)alloc((size_t)HID * E_DIM * 2);
    __hip_bfloat16* w2qT = (__hip_bfloat16*)alloc((size_t)E_DIM * HID * 2);
    __hip_bfloat16* w1kT = (__hip_bfloat16*)alloc((size_t)HID * E_DIM * 2);
    __hip_bfloat16* w2kT = (__hip_bfloat16*)alloc((size_t)E_DIM * HID * 2);
    (void)ws_size; (void)n_in; (void)out_size; (void)in_sizes;

    prep<<<NB_PREP, 256, 0, stream>>>(q_in, key_in, val_in,
                                      q_w1, q_w2, k_w1, k_w2,
                                      qA, kA, kvB, w1qT, w2qT, w1kT, w2kT);

    const float qscale = 0.17677669529663687f;  // 1/sqrt(32)
    gemm_bf16<<<(T_PAD / 128) * (HID / 128), 256, 0, stream>>>(qA, w1qT, q_b1, hidQ, E_DIM, HID, HID, 1, 1.0f);
    gemm_bf16<<<(T_PAD / 128) * (E_DIM / 128), 256, 0, stream>>>(hidQ, w2qT, q_b2, qMl, HID, E_DIM, E_DIM, 0, qscale);
    gemm_bf16<<<(S_K / 128) * (HID / 128), 256, 0, stream>>>(kA, w1kT, k_b1, hidK, E_DIM, HID, HID, 1, 1.0f);
    gemm_bf16<<<(S_K / 128) * (E_DIM / 128), 256, 0, stream>>>(hidK, w2kT, k_b2, kvB, HID, E_DIM, 512, 0, 1.0f);

    attn_kernel<<<T_Q / 4, 256, 0, stream>>>(qMl, kvB, ranks_feat, starts, lens, out);
}